// Round 8
// baseline (443.486 us; speedup 1.0000x reference)
//
#include <hip/hip_runtime.h>

#define C_DIM 256
#define CQK   32
#define N_DIM 4096
#define B_DIM 2

typedef __attribute__((ext_vector_type(8))) short bf16x8;
typedef __attribute__((ext_vector_type(4))) float f32x4;

__device__ __forceinline__ unsigned short f2bf(float f) {
    union { float f; unsigned u; } v; v.f = f;
    unsigned r = v.u + 0x7FFFu + ((v.u >> 16) & 1u);   // RNE
    return (unsigned short)(r >> 16);
}
__device__ __forceinline__ unsigned pk2(float a, float b) {
    return (unsigned)f2bf(a) | ((unsigned)f2bf(b) << 16);
}
// truncating pack via v_perm_b32 (1 VALU op): low16 = bf16_trunc(a), high = b
__device__ __forceinline__ unsigned pk2t(float a, float b) {
    union { float f; unsigned u; } ua, ub; ua.f = a; ub.f = b;
    return __builtin_amdgcn_perm(ub.u, ua.u, 0x07060302u);
}
#define EXP2(x) __builtin_amdgcn_exp2f(x)
#define MFMA(A, B, C) __builtin_amdgcn_mfma_f32_16x16x32_bf16((A), (B), (C), 0, 0, 0)

// P-fragment lane exchange: convert per-lane S layout (lane(lr,lq) holds
// P[j=lq*4+r (+16 for B)][i=lr] packed as A0,A1,B0,B1 bf16-pair words) into
// the PV B-operand layout (lane needs P[i=lr][j=lq*8..lq*8+7] = 4 words).
// 3 shfl_xor exchanges; mapping verified per-lane:
//   lq0 <- {A0,A1,self | A0,A1 of lq1 via x16}            (j 0..7)
//   lq1 <- {A0,A1 of lq2 via x48 | A0,A1 of lq3 via x32}  (j 8..15)
//   lq2 <- {B0,B1 of lq0 via x32 | B0,B1 of lq1 via x48}  (j16..23)
//   lq3 <- {B0,B1 of lq2 via x16 | B0,B1,self}            (j24..31)
__device__ __forceinline__ void pexchange(int lq, unsigned A0, unsigned A1,
                                          unsigned B0, unsigned B1,
                                          unsigned* w) {
    const bool odd = lq & 1, lo = lq < 2;
    unsigned s16a = odd ? A0 : B0, s16b = odd ? A1 : B1;   // x16: odd sends A
    unsigned s32a = lo ? B0 : A0, s32b = lo ? B1 : A1;     // x32/x48: lo sends B
    unsigned r16a = __shfl_xor(s16a, 16), r16b = __shfl_xor(s16b, 16);
    unsigned r32a = __shfl_xor(s32a, 32), r32b = __shfl_xor(s32b, 32);
    unsigned r48a = __shfl_xor(s32a, 48), r48b = __shfl_xor(s32b, 48);
    w[0] = lq == 0 ? A0   : lq == 1 ? r48a : lq == 2 ? r32a : r16a;
    w[1] = lq == 0 ? A1   : lq == 1 ? r48b : lq == 2 ? r32b : r16b;
    w[2] = lq == 0 ? r16a : lq == 1 ? r32a : lq == 2 ? r48a : B0;
    w[3] = lq == 0 ? r16b : lq == 1 ? r32b : lq == 2 ? r48b : B1;
}

// ---------------------------------------------------------------------------
// Kernel 0: convert W (q|k|v rows, 320x256) to bf16 + gather biases.
// q rows (and q bias) pre-scaled by log2(e) so attn uses raw 2^x.
// ---------------------------------------------------------------------------
__global__ __launch_bounds__(256) void wconv(
    const float* __restrict__ q_w, const float* __restrict__ q_b,
    const float* __restrict__ k_w, const float* __restrict__ k_b,
    const float* __restrict__ v_w, const float* __restrict__ v_b,
    unsigned short* __restrict__ wbf, float* __restrict__ biasf)
{
    const float LOG2E = 1.4426950408889634f;
    int o = blockIdx.x, c = threadIdx.x;
    float w;
    if (o < 32)       w = q_w[o * C_DIM + c] * LOG2E;
    else if (o < 64)  w = k_w[(o - 32) * C_DIM + c];
    else              w = v_w[(o - 64) * C_DIM + c];
    wbf[o * C_DIM + c] = f2bf(w);
    if (c == 0) biasf[o] = (o < 32) ? q_b[o] * LOG2E
                         : (o < 64) ? k_b[o - 32] : v_b[o - 64];
}

// ---------------------------------------------------------------------------
// Kernel 1: QKV projection via MFMA, n-tile 32 (proven R5).
// V stored TILED as [b][cs4(4)][jt(128)][c'(64)][j'(32)] bf16 (proven R2).
// ---------------------------------------------------------------------------
__global__ __launch_bounds__(256, 2) void qkv_proj(
    const float* __restrict__ x, const unsigned short* __restrict__ wbf,
    const float* __restrict__ biasf,
    unsigned short* __restrict__ qT, unsigned short* __restrict__ kT,
    unsigned short* __restrict__ vbf)
{
    __shared__ __align__(16) unsigned short xsT[32 * 264];     // [n][c] bf16
    __shared__ __align__(16) unsigned short qkbuf[2][32 * 36]; // q/k bounce
    __shared__ __align__(16) unsigned short vbb[256 * 36];     // v bounce, stride 36
    const int t  = threadIdx.x;
    const int b  = blockIdx.x >> 7;
    const int n0 = (blockIdx.x & 127) * 32;

    {
        int n4 = t & 3, cq = t >> 2;   // cq 0..63, n-octet n4*8
        const float* xp = x + ((size_t)(b * C_DIM + cq * 4)) * N_DIM + n0 + n4 * 8;
        float a0[8], a1[8], a2[8], a3[8];
        *(float4*)(a0)     = *(const float4*)(xp);
        *(float4*)(a0 + 4) = *(const float4*)(xp + 4);
        *(float4*)(a1)     = *(const float4*)(xp + N_DIM);
        *(float4*)(a1 + 4) = *(const float4*)(xp + N_DIM + 4);
        *(float4*)(a2)     = *(const float4*)(xp + 2 * N_DIM);
        *(float4*)(a2 + 4) = *(const float4*)(xp + 2 * N_DIM + 4);
        *(float4*)(a3)     = *(const float4*)(xp + 3 * N_DIM);
        *(float4*)(a3 + 4) = *(const float4*)(xp + 3 * N_DIM + 4);
        #pragma unroll
        for (int k = 0; k < 8; ++k) {
            uint2 pw;
            pw.x = pk2(a0[k], a1[k]);
            pw.y = pk2(a2[k], a3[k]);
            *(uint2*)&xsT[(n4 * 8 + k) * 264 + cq * 4] = pw;
        }
    }
    __syncthreads();

    const int w = t >> 6, lid = t & 63, lr = lid & 15, lq = lid >> 4;
    f32x4 acc[5][2] = {};   // [u][nh]
    #pragma unroll
    for (int ks = 0; ks < 8; ++ks) {
        bf16x8 xb0 = *(const bf16x8*)&xsT[lr * 264 + ks * 32 + lq * 8];
        bf16x8 xb1 = *(const bf16x8*)&xsT[(16 + lr) * 264 + ks * 32 + lq * 8];
        #pragma unroll
        for (int u = 0; u < 5; ++u) {
            int gm = w * 5 + u;
            bf16x8 af = *(const bf16x8*)&wbf[(gm * 16 + lr) * C_DIM + ks * 32 + lq * 8];
            acc[u][0] = MFMA(af, xb0, acc[u][0]);
            acc[u][1] = MFMA(af, xb1, acc[u][1]);
        }
    }
    #pragma unroll
    for (int u = 0; u < 5; ++u) {
        int gm = w * 5 + u;
        float bv[4];
        *(float4*)bv = *(const float4*)&biasf[gm * 16 + lq * 4];
        #pragma unroll
        for (int nh = 0; nh < 2; ++nh) {
            if (gm >= 4) {
                int vc = (gm - 4) * 16 + lq * 4;
                #pragma unroll
                for (int r = 0; r < 4; ++r)
                    vbb[(vc + r) * 36 + nh * 16 + lr] = f2bf(acc[u][nh][r] + bv[r]);
            } else {
                int sel = gm >> 1, half = gm & 1;   // wave 0 only
                uint2 pw;
                pw.x = pk2(acc[u][nh][0] + bv[0], acc[u][nh][1] + bv[1]);
                pw.y = pk2(acc[u][nh][2] + bv[2], acc[u][nh][3] + bv[3]);
                *(uint2*)&qkbuf[sel][(nh * 16 + lr) * 36 + half * 16 + lq * 4] = pw;
            }
        }
    }
    __syncthreads();
    {
        // q/k out: 2 sel x 32 n x 32 ch, 256 threads = one 8-ch chunk each
        int sel = t >> 7, idx = t & 127;
        int n = idx >> 2, ch8 = (idx & 3) * 8;
        const unsigned short* src = &qkbuf[sel][n * 36 + ch8];
        uint2 a = *(const uint2*)src;
        uint2 c = *(const uint2*)(src + 4);
        unsigned short* dst = (sel ? kT : qT) + ((size_t)b * N_DIM + n0 + n) * CQK + ch8;
        uint4 st; st.x = a.x; st.y = a.y; st.z = c.x; st.w = c.y;
        *(uint4*)dst = st;
    }
    {
        // V store: n-tile 32 = exactly one tile (b, cs4=t>>6, jt=n0>>5);
        // thread t writes its channel row (64B contiguous, fully coalesced)
        const unsigned short* src = &vbb[t * 36];
        uint2 a = *(const uint2*)(src + 0);
        uint2 bq = *(const uint2*)(src + 4);
        uint2 c = *(const uint2*)(src + 8);
        uint2 d = *(const uint2*)(src + 12);
        uint2 e = *(const uint2*)(src + 16);
        uint2 f = *(const uint2*)(src + 20);
        uint2 g = *(const uint2*)(src + 24);
        uint2 h = *(const uint2*)(src + 28);
        unsigned short* dst = vbf +
            (((size_t)(b * 4 + (t >> 6)) * 128 + (n0 >> 5)) * 64 + (t & 63)) * 32;
        uint4 s0; s0.x = a.x; s0.y = a.y; s0.z = bq.x; s0.w = bq.y;
        uint4 s1; s1.x = c.x; s1.y = c.y; s1.z = d.x; s1.w = d.y;
        uint4 s2; s2.x = e.x; s2.y = e.y; s2.z = f.x; s2.w = f.y;
        uint4 s3; s3.x = g.x; s3.y = g.y; s3.z = h.x; s3.w = h.y;
        *(uint4*)(dst)      = s0;
        *(uint4*)(dst + 8)  = s1;
        *(uint4*)(dst + 16) = s2;
        *(uint4*)(dst + 24) = s3;
    }
}

// ---------------------------------------------------------------------------
// Kernel 2: MFMA flash attention — R8: EXACT R2/R5 geometry and schedule
// (i=64, cs=4, 4-wave j-split, 32 iters, 6 loads/iter, prefetch-1, 1-iter
// P pipeline, barrier-free loop), with ONE component swap: P lives in
// REGISTERS via the 6-shuffle lane exchange (pexchange) instead of the LDS
// round-trip. Removes: 3.1M bank-conflict cycles (~12% of runtime), 12 LDS
// ops/iter + lgkmcnt waits on the PV critical path, and 40KB of LDS.
// R3/R6/R7 lesson: geometry changes away from R2 always lose; this changes
// no geometry, only the P transport mechanism.
// grid: b(2) x qt(64) x cs(4) = 512 blocks, 256 threads (4 waves x 1024 j).
// ---------------------------------------------------------------------------
__global__ __launch_bounds__(256, 2) void attn_kernel(
    const unsigned short* __restrict__ qT, const unsigned short* __restrict__ kT,
    const unsigned short* __restrict__ vbf, const float* __restrict__ x,
    const float* __restrict__ gamma, float* __restrict__ out)
{
    // LDS: obuf [64 c][68] f32 = 17408B; lbuf 4*64 partial + 64 linv = 1280B.
    __shared__ __align__(16) char smem[17408 + 1536];
    float* obuf = (float*)smem;
    float* lbuf = (float*)(smem + 17408);

    const int t  = threadIdx.x;
    const int b  = blockIdx.x >> 8;
    const int qt = (blockIdx.x >> 2) & 63;
    const int cs = blockIdx.x & 3;
    const int i0 = qt * 64;
    const int w = t >> 6, lid = t & 63, lr = lid & 15, lq = lid >> 4;

    const unsigned short* qTb = qT + (size_t)b * N_DIM * CQK;
    const unsigned short* kTb = kT + (size_t)b * N_DIM * CQK;
    // tiled V base for this (b, cs): 128 tiles x 2048 shorts
    const unsigned short* vtb = vbf + (size_t)(b * 4 + cs) * 128 * 2048;

    bf16x8 bq[4];
    #pragma unroll
    for (int it = 0; it < 4; ++it)
        bq[it] = *(const bf16x8*)&qTb[(i0 + it * 16 + lr) * CQK + lq * 8];

    f32x4 oa[4][4] = {};   // [ct][it]
    float lp[4] = {};
    unsigned pP[4][4];     // P(k-1) fragments in registers: [it][word]

    const int jwbase = w * 1024;   // 32 iters of 32 j
    const int vlane = lr * 32 + lq * 8;   // lane offset within a 64x32 V tile

    // prologue: K(0)
    bf16x8 akc0 = *(const bf16x8*)&kTb[(jwbase + lr) * CQK + lq * 8];
    bf16x8 akc1 = *(const bf16x8*)&kTb[(jwbase + 16 + lr) * CQK + lq * 8];
    bf16x8 avU[4];   // V(k-1), consumed by PV at iter k

    // ---- peeled iter 0: S(0)+exp -> P(0) in registers; issue V(0), K(1) ----
    {
        const unsigned short* vt0 = vtb + (size_t)(w * 32) * 2048;
        #pragma unroll
        for (int ct = 0; ct < 4; ++ct)
            avU[ct] = *(const bf16x8*)&vt0[ct * 512 + vlane];
        bf16x8 akn0 = *(const bf16x8*)&kTb[(jwbase + 32 + lr) * CQK + lq * 8];
        bf16x8 akn1 = *(const bf16x8*)&kTb[(jwbase + 32 + 16 + lr) * CQK + lq * 8];
        const f32x4 z = {};
        #pragma unroll
        for (int it = 0; it < 4; ++it) {
            f32x4 s0 = MFMA(akc0, bq[it], z);
            f32x4 s1 = MFMA(akc1, bq[it], z);
            float e0 = EXP2(s0[0]), e1 = EXP2(s0[1]), e2 = EXP2(s0[2]), e3 = EXP2(s0[3]);
            float f0 = EXP2(s1[0]), f1 = EXP2(s1[1]), f2 = EXP2(s1[2]), f3 = EXP2(s1[3]);
            lp[it] += ((e0 + e1) + (e2 + e3)) + ((f0 + f1) + (f2 + f3));
            unsigned A0 = pk2t(e0, e1), A1 = pk2t(e2, e3);
            unsigned B0 = pk2t(f0, f1), B1 = pk2t(f2, f3);
            pexchange(lq, A0, A1, B0, B1, pP[it]);
        }
        akc0 = akn0; akc1 = akn1;
    }

    // ---- steady state k = 1..31 ----
    #pragma unroll 2
    for (int k = 1; k < 32; ++k) {
        const int jn = jwbase + ((k + 1) & 31) * 32;
        // V(k) in flight (consumed by PV at iter k+1 / drain) — contiguous tile
        const unsigned short* vtk = vtb + (size_t)(w * 32 + k) * 2048;
        bf16x8 avI[4];
        #pragma unroll
        for (int ct = 0; ct < 4; ++ct)
            avI[ct] = *(const bf16x8*)&vtk[ct * 512 + vlane];
        // K(k+1) in flight
        bf16x8 akn0 = *(const bf16x8*)&kTb[(jn + lr) * CQK + lq * 8];
        bf16x8 akn1 = *(const bf16x8*)&kTb[(jn + 16 + lr) * CQK + lq * 8];
        // P(k-1) fragments: register copies (free), no LDS dependency
        bf16x8 bp[4];
        #pragma unroll
        for (int it = 0; it < 4; ++it) {
            union { unsigned u[4]; bf16x8 v; } ub;
            ub.u[0] = pP[it][0]; ub.u[1] = pP[it][1];
            ub.u[2] = pP[it][2]; ub.u[3] = pP[it][3];
            bp[it] = ub.v;
        }
        // S(k)
        const f32x4 z = {};
        f32x4 s[4][2];
        #pragma unroll
        for (int it = 0; it < 4; ++it) {
            s[it][0] = MFMA(akc0, bq[it], z);
            s[it][1] = MFMA(akc1, bq[it], z);
        }
        // PV(k-1): overlaps the exp/exchange below via matrix-vs-trans pipes
        #pragma unroll
        for (int it = 0; it < 4; ++it)
            #pragma unroll
            for (int ct = 0; ct < 4; ++ct)
                oa[ct][it] = MFMA(avU[ct], bp[it], oa[ct][it]);
        // exp + pack + exchange -> P(k) registers
        #pragma unroll
        for (int it = 0; it < 4; ++it) {
            float e0 = EXP2(s[it][0][0]), e1 = EXP2(s[it][0][1]);
            float e2 = EXP2(s[it][0][2]), e3 = EXP2(s[it][0][3]);
            float f0 = EXP2(s[it][1][0]), f1 = EXP2(s[it][1][1]);
            float f2 = EXP2(s[it][1][2]), f3 = EXP2(s[it][1][3]);
            lp[it] += ((e0 + e1) + (e2 + e3)) + ((f0 + f1) + (f2 + f3));
            unsigned A0 = pk2t(e0, e1), A1 = pk2t(e2, e3);
            unsigned B0 = pk2t(f0, f1), B1 = pk2t(f2, f3);
            pexchange(lq, A0, A1, B0, B1, pP[it]);
        }
        // rotate
        akc0 = akn0; akc1 = akn1;
        #pragma unroll
        for (int ct = 0; ct < 4; ++ct) avU[ct] = avI[ct];
    }

    // ---- drain: PV(31) from register P ----
    {
        #pragma unroll
        for (int it = 0; it < 4; ++it) {
            union { unsigned u[4]; bf16x8 v; } ub;
            ub.u[0] = pP[it][0]; ub.u[1] = pP[it][1];
            ub.u[2] = pP[it][2]; ub.u[3] = pP[it][3];
            bf16x8 bp = ub.v;
            #pragma unroll
            for (int ct = 0; ct < 4; ++ct)
                oa[ct][it] = MFMA(avU[ct], bp, oa[ct][it]);
        }
    }

    // ---- l: reduce across lq within wave ----
    #pragma unroll
    for (int it = 0; it < 4; ++it) {
        lp[it] += __shfl_xor(lp[it], 16);
        lp[it] += __shfl_xor(lp[it], 32);
    }
    if (lq == 0) {
        #pragma unroll
        for (int it = 0; it < 4; ++it)
            lbuf[w * 64 + it * 16 + lr] = lp[it];
    }
    __syncthreads();

    // ---- sequential cross-wave O accumulate into obuf[c][i] ----
    for (int ph = 0; ph < 4; ++ph) {
        if (w == ph) {
            #pragma unroll
            for (int ct = 0; ct < 4; ++ct)
                #pragma unroll
                for (int it = 0; it < 4; ++it)
                    #pragma unroll
                    for (int r = 0; r < 4; ++r) {
                        int addr = (ct * 16 + lq * 4 + r) * 68 + it * 16 + lr;
                        if (ph == 0) obuf[addr]  = oa[ct][it][r];
                        else         obuf[addr] += oa[ct][it][r];
                    }
        }
        __syncthreads();
    }
    if (t < 64) {
        float l = lbuf[t] + lbuf[64 + t] + lbuf[128 + t] + lbuf[192 + t];
        lbuf[256 + t] = 1.f / l;
    }
    __syncthreads();

    // ---- epilogue: out = gamma*O/l + x ----
    const float g2 = gamma[0];
    const int c0 = cs * 64;
    const int cc = t >> 2;
    const int ic = (t & 3) * 16;
    const size_t rowbase = ((size_t)b * C_DIM + c0 + cc) * N_DIM + i0 + ic;
    #pragma unroll
    for (int k = 0; k < 4; ++k) {
        float4 ov4 = *(const float4*)&obuf[cc * 68 + ic + k * 4];
        float4 li  = *(const float4*)&lbuf[256 + ic + k * 4];
        float4 xv  = *(const float4*)(x + rowbase + k * 4);
        float4 ov;
        ov.x = g2 * ov4.x * li.x + xv.x;
        ov.y = g2 * ov4.y * li.y + xv.y;
        ov.z = g2 * ov4.z * li.z + xv.z;
        ov.w = g2 * ov4.w * li.w + xv.w;
        *(float4*)(out + rowbase + k * 4) = ov;
    }
}

extern "C" void kernel_launch(void* const* d_in, const int* in_sizes, int n_in,
                              void* d_out, int out_size, void* d_ws, size_t ws_size,
                              hipStream_t stream) {
    const float* x     = (const float*)d_in[0];
    const float* q_w   = (const float*)d_in[1];
    const float* q_b   = (const float*)d_in[2];
    const float* k_w   = (const float*)d_in[3];
    const float* k_b   = (const float*)d_in[4];
    const float* v_w   = (const float*)d_in[5];
    const float* v_b   = (const float*)d_in[6];
    const float* gamma = (const float*)d_in[7];
    float* out = (float*)d_out;

    char* ws = (char*)d_ws;
    unsigned short* qT    = (unsigned short*)(ws);             // 512KB
    unsigned short* kT    = (unsigned short*)(ws + 524288);    // 512KB
    unsigned short* vbf   = (unsigned short*)(ws + 1048576);   // 4MB (tiled)
    unsigned short* wbf   = (unsigned short*)(ws + 5242880);   // 160KB
    float*          biasf = (float*)(ws + 5406720);            // 1.25KB

    hipLaunchKernelGGL(wconv, dim3(320), dim3(256), 0, stream,
                       q_w, q_b, k_w, k_b, v_w, v_b, wbf, biasf);
    hipLaunchKernelGGL(qkv_proj, dim3(B_DIM * 128), dim3(256), 0, stream,
                       x, wbf, biasf, qT, kT, vbf);
    hipLaunchKernelGGL(attn_kernel, dim3(B_DIM * 64 * 4), dim3(256), 0, stream,
                       qT, kT, vbf, x, gamma, out);
}

// Round 9
// 118.120 us; speedup vs baseline: 3.7545x; 3.7545x over previous
//
#include <hip/hip_runtime.h>

#define C_DIM 256
#define CQK   32
#define N_DIM 4096
#define B_DIM 2

typedef __attribute__((ext_vector_type(8))) short bf16x8;
typedef __attribute__((ext_vector_type(4))) float f32x4;

__device__ __forceinline__ unsigned short f2bf(float f) {
    union { float f; unsigned u; } v; v.f = f;
    unsigned r = v.u + 0x7FFFu + ((v.u >> 16) & 1u);   // RNE
    return (unsigned short)(r >> 16);
}
__device__ __forceinline__ unsigned pk2(float a, float b) {
    return (unsigned)f2bf(a) | ((unsigned)f2bf(b) << 16);
}
// truncating pack via v_perm_b32 (1 VALU op): low16 = bf16_trunc(a), high = b
__device__ __forceinline__ unsigned pk2t(float a, float b) {
    union { float f; unsigned u; } ua, ub; ua.f = a; ub.f = b;
    return __builtin_amdgcn_perm(ub.u, ua.u, 0x07060302u);
}
#define EXP2(x) __builtin_amdgcn_exp2f(x)
#define MFMA(A, B, C) __builtin_amdgcn_mfma_f32_16x16x32_bf16((A), (B), (C), 0, 0, 0)

// ---------------------------------------------------------------------------
// Kernel 0: convert W (q|k|v rows, 320x256) to bf16 + gather biases.
// q rows (and q bias) pre-scaled by log2(e) so attn uses raw 2^x.
// ---------------------------------------------------------------------------
__global__ __launch_bounds__(256) void wconv(
    const float* __restrict__ q_w, const float* __restrict__ q_b,
    const float* __restrict__ k_w, const float* __restrict__ k_b,
    const float* __restrict__ v_w, const float* __restrict__ v_b,
    unsigned short* __restrict__ wbf, float* __restrict__ biasf)
{
    const float LOG2E = 1.4426950408889634f;
    int o = blockIdx.x, c = threadIdx.x;
    float w;
    if (o < 32)       w = q_w[o * C_DIM + c] * LOG2E;
    else if (o < 64)  w = k_w[(o - 32) * C_DIM + c];
    else              w = v_w[(o - 64) * C_DIM + c];
    wbf[o * C_DIM + c] = f2bf(w);
    if (c == 0) biasf[o] = (o < 32) ? q_b[o] * LOG2E
                         : (o < 64) ? k_b[o - 32] : v_b[o - 64];
}

// ---------------------------------------------------------------------------
// Kernel 1: QKV projection via MFMA, n-tile 32 (proven R5).
// V stored TILED as [b][cs4(4)][jt(128)][c'(64)][j'(32)] bf16 (proven R2).
// ---------------------------------------------------------------------------
__global__ __launch_bounds__(256, 2) void qkv_proj(
    const float* __restrict__ x, const unsigned short* __restrict__ wbf,
    const float* __restrict__ biasf,
    unsigned short* __restrict__ qT, unsigned short* __restrict__ kT,
    unsigned short* __restrict__ vbf)
{
    __shared__ __align__(16) unsigned short xsT[32 * 264];     // [n][c] bf16
    __shared__ __align__(16) unsigned short qkbuf[2][32 * 36]; // q/k bounce
    __shared__ __align__(16) unsigned short vbb[256 * 36];     // v bounce, stride 36
    const int t  = threadIdx.x;
    const int b  = blockIdx.x >> 7;
    const int n0 = (blockIdx.x & 127) * 32;

    {
        int n4 = t & 3, cq = t >> 2;   // cq 0..63, n-octet n4*8
        const float* xp = x + ((size_t)(b * C_DIM + cq * 4)) * N_DIM + n0 + n4 * 8;
        float a0[8], a1[8], a2[8], a3[8];
        *(float4*)(a0)     = *(const float4*)(xp);
        *(float4*)(a0 + 4) = *(const float4*)(xp + 4);
        *(float4*)(a1)     = *(const float4*)(xp + N_DIM);
        *(float4*)(a1 + 4) = *(const float4*)(xp + N_DIM + 4);
        *(float4*)(a2)     = *(const float4*)(xp + 2 * N_DIM);
        *(float4*)(a2 + 4) = *(const float4*)(xp + 2 * N_DIM + 4);
        *(float4*)(a3)     = *(const float4*)(xp + 3 * N_DIM);
        *(float4*)(a3 + 4) = *(const float4*)(xp + 3 * N_DIM + 4);
        #pragma unroll
        for (int k = 0; k < 8; ++k) {
            uint2 pw;
            pw.x = pk2(a0[k], a1[k]);
            pw.y = pk2(a2[k], a3[k]);
            *(uint2*)&xsT[(n4 * 8 + k) * 264 + cq * 4] = pw;
        }
    }
    __syncthreads();

    const int w = t >> 6, lid = t & 63, lr = lid & 15, lq = lid >> 4;
    f32x4 acc[5][2] = {};   // [u][nh]
    #pragma unroll
    for (int ks = 0; ks < 8; ++ks) {
        bf16x8 xb0 = *(const bf16x8*)&xsT[lr * 264 + ks * 32 + lq * 8];
        bf16x8 xb1 = *(const bf16x8*)&xsT[(16 + lr) * 264 + ks * 32 + lq * 8];
        #pragma unroll
        for (int u = 0; u < 5; ++u) {
            int gm = w * 5 + u;
            bf16x8 af = *(const bf16x8*)&wbf[(gm * 16 + lr) * C_DIM + ks * 32 + lq * 8];
            acc[u][0] = MFMA(af, xb0, acc[u][0]);
            acc[u][1] = MFMA(af, xb1, acc[u][1]);
        }
    }
    #pragma unroll
    for (int u = 0; u < 5; ++u) {
        int gm = w * 5 + u;
        float bv[4];
        *(float4*)bv = *(const float4*)&biasf[gm * 16 + lq * 4];
        #pragma unroll
        for (int nh = 0; nh < 2; ++nh) {
            if (gm >= 4) {
                int vc = (gm - 4) * 16 + lq * 4;
                #pragma unroll
                for (int r = 0; r < 4; ++r)
                    vbb[(vc + r) * 36 + nh * 16 + lr] = f2bf(acc[u][nh][r] + bv[r]);
            } else {
                int sel = gm >> 1, half = gm & 1;   // wave 0 only
                uint2 pw;
                pw.x = pk2(acc[u][nh][0] + bv[0], acc[u][nh][1] + bv[1]);
                pw.y = pk2(acc[u][nh][2] + bv[2], acc[u][nh][3] + bv[3]);
                *(uint2*)&qkbuf[sel][(nh * 16 + lr) * 36 + half * 16 + lq * 4] = pw;
            }
        }
    }
    __syncthreads();
    {
        // q/k out: 2 sel x 32 n x 32 ch, 256 threads = one 8-ch chunk each
        int sel = t >> 7, idx = t & 127;
        int n = idx >> 2, ch8 = (idx & 3) * 8;
        const unsigned short* src = &qkbuf[sel][n * 36 + ch8];
        uint2 a = *(const uint2*)src;
        uint2 c = *(const uint2*)(src + 4);
        unsigned short* dst = (sel ? kT : qT) + ((size_t)b * N_DIM + n0 + n) * CQK + ch8;
        uint4 st; st.x = a.x; st.y = a.y; st.z = c.x; st.w = c.y;
        *(uint4*)dst = st;
    }
    {
        // V store: n-tile 32 = exactly one tile (b, cs4=t>>6, jt=n0>>5);
        // thread t writes its channel row (64B contiguous, fully coalesced)
        const unsigned short* src = &vbb[t * 36];
        uint2 a = *(const uint2*)(src + 0);
        uint2 bq = *(const uint2*)(src + 4);
        uint2 c = *(const uint2*)(src + 8);
        uint2 d = *(const uint2*)(src + 12);
        uint2 e = *(const uint2*)(src + 16);
        uint2 f = *(const uint2*)(src + 20);
        uint2 g = *(const uint2*)(src + 24);
        uint2 h = *(const uint2*)(src + 28);
        unsigned short* dst = vbf +
            (((size_t)(b * 4 + (t >> 6)) * 128 + (n0 >> 5)) * 64 + (t & 63)) * 32;
        uint4 s0; s0.x = a.x; s0.y = a.y; s0.z = bq.x; s0.w = bq.y;
        uint4 s1; s1.x = c.x; s1.y = c.y; s1.z = d.x; s1.w = d.y;
        uint4 s2; s2.x = e.x; s2.y = e.y; s2.z = f.x; s2.w = f.y;
        uint4 s3; s3.x = g.x; s3.y = g.y; s3.z = h.x; s3.w = h.y;
        *(uint4*)(dst)      = s0;
        *(uint4*)(dst + 8)  = s1;
        *(uint4*)(dst + 16) = s2;
        *(uint4*)(dst + 24) = s3;
    }
}

// ---------------------------------------------------------------------------
// Kernel 2: MFMA flash attention — R9: EXACT R2/R5 structure (i=64, cs=4,
// 4-wave j-split, 32 iters, 6 loads/iter, prefetch-1, double-buffered
// wave-private P in LDS, barrier-free loop) with ONE change: P layout is
// XOR-SWIZZLED (guide G4 recipe, HW-verified for this exact pattern: lanes
// reading different rows at same col via ds_read_b128). Row stride -> 128B,
// byte col ^= (row&7)<<4. The 3.15M bank-conflict cycles (~48 cy/wave-iter,
// ~12% of runtime, sitting on the PV critical path via the b128 P read) go
// to ~0. XOR mask is loop-invariant per lane (folded into precomputed col
// offsets) -> zero extra per-iter VALU. P = 64KB; block 67KB x2 = 134KB
// <= 160KB -> 2 blocks/CU preserved. R8's register-P approach is dead
// (pointer-taking -> scratch spill, and 24 shuffles/iter > 12 LDS ops).
// grid: b(2) x qt(64) x cs(4) = 512 blocks, 256 threads (4 waves x 1024 j).
// ---------------------------------------------------------------------------
__global__ __launch_bounds__(256, 2) void attn_kernel(
    const unsigned short* __restrict__ qT, const unsigned short* __restrict__ kT,
    const unsigned short* __restrict__ vbf, const float* __restrict__ x,
    const float* __restrict__ gamma, float* __restrict__ out)
{
    // P: 4 waves x 2 bufs x [64 i][stride 64] bf16 = 65536B (swizzled cols).
    // obuf overlays P after the loop ([64 c][68] f32 = 17408B).
    // lbuf: [4][64] partial l + [64] linv = 1280B.
    __shared__ __align__(16) char smem[65536 + 1536];
    char* pbase = smem;
    float* obuf = (float*)smem;
    float* lbuf = (float*)(smem + 65536);

    const int t  = threadIdx.x;
    const int b  = blockIdx.x >> 8;
    const int qt = (blockIdx.x >> 2) & 63;
    const int cs = blockIdx.x & 3;
    const int i0 = qt * 64;
    const int w = t >> 6, lid = t & 63, lr = lid & 15, lq = lid >> 4;

    const unsigned short* qTb = qT + (size_t)b * N_DIM * CQK;
    const unsigned short* kTb = kT + (size_t)b * N_DIM * CQK;
    // tiled V base for this (b, cs): 128 tiles x 2048 shorts
    const unsigned short* vtb = vbf + (size_t)(b * 4 + cs) * 128 * 2048;

    // swizzled-P per-lane constants: row = it*16+lr (128B rows), mask from lr
    const int pmask = (lr & 7) << 4;                   // byte XOR mask
    const int wcol0 = (lq * 8) ^ pmask;                // write cols (8B units)
    const int wcol1 = (32 + lq * 8) ^ pmask;
    const int rcol  = (lq * 16) ^ pmask;               // read col (16B unit)
    char* pW0 = pbase + (w * 2 + 0) * (64 * 128) + lr * 128;
    char* pW1 = pbase + (w * 2 + 1) * (64 * 128) + lr * 128;

    bf16x8 bq[4];
    #pragma unroll
    for (int it = 0; it < 4; ++it)
        bq[it] = *(const bf16x8*)&qTb[(i0 + it * 16 + lr) * CQK + lq * 8];

    f32x4 oa[4][4] = {};   // [ct][it]
    float lp[4] = {};

    const int jwbase = w * 1024;   // 32 iters of 32 j
    const int vlane = lr * 32 + lq * 8;   // lane offset within a 64x32 V tile

    // prologue: K(0)
    bf16x8 akc0 = *(const bf16x8*)&kTb[(jwbase + lr) * CQK + lq * 8];
    bf16x8 akc1 = *(const bf16x8*)&kTb[(jwbase + 16 + lr) * CQK + lq * 8];
    bf16x8 avU[4];   // V(k-1), consumed by PV at iter k

    // ---- peeled iter 0: S(0)+exp -> P(0) in pW0; issue V(0), K(1) ----
    {
        const unsigned short* vt0 = vtb + (size_t)(w * 32) * 2048;
        #pragma unroll
        for (int ct = 0; ct < 4; ++ct)
            avU[ct] = *(const bf16x8*)&vt0[ct * 512 + vlane];
        bf16x8 akn0 = *(const bf16x8*)&kTb[(jwbase + 32 + lr) * CQK + lq * 8];
        bf16x8 akn1 = *(const bf16x8*)&kTb[(jwbase + 32 + 16 + lr) * CQK + lq * 8];
        const f32x4 z = {};
        #pragma unroll
        for (int it = 0; it < 4; ++it) {
            f32x4 s0 = MFMA(akc0, bq[it], z);
            f32x4 s1 = MFMA(akc1, bq[it], z);
            float e0 = EXP2(s0[0]), e1 = EXP2(s0[1]), e2 = EXP2(s0[2]), e3 = EXP2(s0[3]);
            float f0 = EXP2(s1[0]), f1 = EXP2(s1[1]), f2 = EXP2(s1[2]), f3 = EXP2(s1[3]);
            lp[it] += ((e0 + e1) + (e2 + e3)) + ((f0 + f1) + (f2 + f3));
            uint2 pw0; pw0.x = pk2t(e0, e1); pw0.y = pk2t(e2, e3);
            uint2 pw1; pw1.x = pk2t(f0, f1); pw1.y = pk2t(f2, f3);
            char* prow = pW0 + it * 16 * 128;
            *(uint2*)(prow + wcol0) = pw0;
            *(uint2*)(prow + wcol1) = pw1;
        }
        akc0 = akn0; akc1 = akn1;
    }

    // ---- steady state k = 1..31 ----
    #pragma unroll 2
    for (int k = 1; k < 32; ++k) {
        const int jn = jwbase + ((k + 1) & 31) * 32;
        // V(k) in flight (consumed by PV at iter k+1 / drain) — contiguous tile
        const unsigned short* vtk = vtb + (size_t)(w * 32 + k) * 2048;
        bf16x8 avI[4];
        #pragma unroll
        for (int ct = 0; ct < 4; ++ct)
            avI[ct] = *(const bf16x8*)&vtk[ct * 512 + vlane];
        // K(k+1) in flight
        bf16x8 akn0 = *(const bf16x8*)&kTb[(jn + lr) * CQK + lq * 8];
        bf16x8 akn1 = *(const bf16x8*)&kTb[(jn + 16 + lr) * CQK + lq * 8];
        // P(k-1) reads from buf[(k-1)&1] — no dependency on this iter's work
        const char* pR = (k & 1) ? pW0 : pW1;
        bf16x8 bp[4];
        #pragma unroll
        for (int it = 0; it < 4; ++it)
            bp[it] = *(const bf16x8*)(pR + it * 16 * 128 + rcol);
        // S(k)
        const f32x4 z = {};
        f32x4 s[4][2];
        #pragma unroll
        for (int it = 0; it < 4; ++it) {
            s[it][0] = MFMA(akc0, bq[it], z);
            s[it][1] = MFMA(akc1, bq[it], z);
        }
        // PV(k-1): overlaps the exp/pack below via matrix-vs-trans pipes
        #pragma unroll
        for (int it = 0; it < 4; ++it)
            #pragma unroll
            for (int ct = 0; ct < 4; ++ct)
                oa[ct][it] = MFMA(avU[ct], bp[it], oa[ct][it]);
        // exp + pack + write P(k) to buf[k&1]
        char* pWc = (k & 1) ? pW1 : pW0;
        #pragma unroll
        for (int it = 0; it < 4; ++it) {
            float e0 = EXP2(s[it][0][0]), e1 = EXP2(s[it][0][1]);
            float e2 = EXP2(s[it][0][2]), e3 = EXP2(s[it][0][3]);
            float f0 = EXP2(s[it][1][0]), f1 = EXP2(s[it][1][1]);
            float f2 = EXP2(s[it][1][2]), f3 = EXP2(s[it][1][3]);
            lp[it] += ((e0 + e1) + (e2 + e3)) + ((f0 + f1) + (f2 + f3));
            uint2 pw0; pw0.x = pk2t(e0, e1); pw0.y = pk2t(e2, e3);
            uint2 pw1; pw1.x = pk2t(f0, f1); pw1.y = pk2t(f2, f3);
            char* prow = pWc + it * 16 * 128;
            *(uint2*)(prow + wcol0) = pw0;
            *(uint2*)(prow + wcol1) = pw1;
        }
        // rotate
        akc0 = akn0; akc1 = akn1;
        #pragma unroll
        for (int ct = 0; ct < 4; ++ct) avU[ct] = avI[ct];
    }

    // ---- drain: PV(31), P(31) in pW1 ----
    {
        bf16x8 bp[4];
        #pragma unroll
        for (int it = 0; it < 4; ++it)
            bp[it] = *(const bf16x8*)(pW1 + it * 16 * 128 + rcol);
        #pragma unroll
        for (int it = 0; it < 4; ++it)
            #pragma unroll
            for (int ct = 0; ct < 4; ++ct)
                oa[ct][it] = MFMA(avU[ct], bp[it], oa[ct][it]);
    }

    // ---- l: reduce across lq within wave ----
    #pragma unroll
    for (int it = 0; it < 4; ++it) {
        lp[it] += __shfl_xor(lp[it], 16);
        lp[it] += __shfl_xor(lp[it], 32);
    }
    if (lq == 0) {
        #pragma unroll
        for (int it = 0; it < 4; ++it)
            lbuf[w * 64 + it * 16 + lr] = lp[it];
    }
    __syncthreads();   // all waves done; P regions dead -> obuf overlay ok

    // ---- sequential cross-wave O accumulate into obuf[c][i] ----
    for (int ph = 0; ph < 4; ++ph) {
        if (w == ph) {
            #pragma unroll
            for (int ct = 0; ct < 4; ++ct)
                #pragma unroll
                for (int it = 0; it < 4; ++it)
                    #pragma unroll
                    for (int r = 0; r < 4; ++r) {
                        int addr = (ct * 16 + lq * 4 + r) * 68 + it * 16 + lr;
                        if (ph == 0) obuf[addr]  = oa[ct][it][r];
                        else         obuf[addr] += oa[ct][it][r];
                    }
        }
        __syncthreads();
    }
    if (t < 64) {
        float l = lbuf[t] + lbuf[64 + t] + lbuf[128 + t] + lbuf[192 + t];
        lbuf[256 + t] = 1.f / l;
    }
    __syncthreads();

    // ---- epilogue: out = gamma*O/l + x ----
    const float g2 = gamma[0];
    const int c0 = cs * 64;
    const int cc = t >> 2;
    const int ic = (t & 3) * 16;
    const size_t rowbase = ((size_t)b * C_DIM + c0 + cc) * N_DIM + i0 + ic;
    #pragma unroll
    for (int k = 0; k < 4; ++k) {
        float4 ov4 = *(const float4*)&obuf[cc * 68 + ic + k * 4];
        float4 li  = *(const float4*)&lbuf[256 + ic + k * 4];
        float4 xv  = *(const float4*)(x + rowbase + k * 4);
        float4 ov;
        ov.x = g2 * ov4.x * li.x + xv.x;
        ov.y = g2 * ov4.y * li.y + xv.y;
        ov.z = g2 * ov4.z * li.z + xv.z;
        ov.w = g2 * ov4.w * li.w + xv.w;
        *(float4*)(out + rowbase + k * 4) = ov;
    }
}

extern "C" void kernel_launch(void* const* d_in, const int* in_sizes, int n_in,
                              void* d_out, int out_size, void* d_ws, size_t ws_size,
                              hipStream_t stream) {
    const float* x     = (const float*)d_in[0];
    const float* q_w   = (const float*)d_in[1];
    const float* q_b   = (const float*)d_in[2];
    const float* k_w   = (const float*)d_in[3];
    const float* k_b   = (const float*)d_in[4];
    const float* v_w   = (const float*)d_in[5];
    const float* v_b   = (const float*)d_in[6];
    const float* gamma = (const float*)d_in[7];
    float* out = (float*)d_out;

    char* ws = (char*)d_ws;
    unsigned short* qT    = (unsigned short*)(ws);             // 512KB
    unsigned short* kT    = (unsigned short*)(ws + 524288);    // 512KB
    unsigned short* vbf   = (unsigned short*)(ws + 1048576);   // 4MB (tiled)
    unsigned short* wbf   = (unsigned short*)(ws + 5242880);   // 160KB
    float*          biasf = (float*)(ws + 5406720);            // 1.25KB

    hipLaunchKernelGGL(wconv, dim3(320), dim3(256), 0, stream,
                       q_w, q_b, k_w, k_b, v_w, v_b, wbf, biasf);
    hipLaunchKernelGGL(qkv_proj, dim3(B_DIM * 128), dim3(256), 0, stream,
                       x, wbf, biasf, qT, kT, vbf);
    hipLaunchKernelGGL(attn_kernel, dim3(B_DIM * 64 * 4), dim3(256), 0, stream,
                       qT, kT, vbf, x, gamma, out);
}